// Round 1
// baseline (171.034 us; speedup 1.0000x reference)
//
#include <hip/hip_runtime.h>
#include <hip/hip_bf16.h>

#define N_TOK 16384
#define DIM   1024
#define NE    8
#define NR    4

typedef __bf16 bf16_t;
typedef __bf16 bf16x4_t __attribute__((ext_vector_type(4)));
typedef __bf16 bf16x8_t __attribute__((ext_vector_type(8)));
typedef float  f32x4_t  __attribute__((ext_vector_type(4)));

// ---------------------------------------------------------------------------
// Kernel 1: gating + LoRA "t" coefficients. One wave (64 lanes) per token.
// Writes coef[n][8] = w_k * t[k][r]  (k in {0,1}, r in {0..3}) and idx[n][2].
// All fp32 to match reference top-k selection as closely as possible.
// ---------------------------------------------------------------------------
__global__ __launch_bounds__(256) void gate_coef_kernel(
    const float* __restrict__ x, const float* __restrict__ gate_w,
    const float* __restrict__ left, float* __restrict__ coef,
    int* __restrict__ idxs)
{
    const int lane = threadIdx.x & 63;
    const int wid  = threadIdx.x >> 6;
    const int n    = blockIdx.x * 4 + wid;

    const float4* x4 = reinterpret_cast<const float4*>(x + (size_t)n * DIM);
    float4 xr[4];
#pragma unroll
    for (int i = 0; i < 4; ++i) xr[i] = x4[lane + i * 64];

    // 8 gate logits (dot over D=1024), full-wave butterfly reduction
    float logit[NE];
#pragma unroll
    for (int e = 0; e < NE; ++e) {
        const float4* g4 = reinterpret_cast<const float4*>(gate_w + (size_t)e * DIM);
        float p = 0.f;
#pragma unroll
        for (int i = 0; i < 4; ++i) {
            float4 g = g4[lane + i * 64];
            p += xr[i].x * g.x + xr[i].y * g.y + xr[i].z * g.z + xr[i].w * g.w;
        }
#pragma unroll
        for (int off = 32; off > 0; off >>= 1) p += __shfl_xor(p, off, 64);
        logit[e] = p;
    }

    // top-2 on logits (softmax is monotonic); ties -> lowest index, like lax.top_k
    int i0 = 0;
#pragma unroll
    for (int e = 1; e < NE; ++e) if (logit[e] > logit[i0]) i0 = e;
    int i1 = (i0 == 0) ? 1 : 0;
#pragma unroll
    for (int e = 0; e < NE; ++e) {
        if (e == i0) continue;
        if (logit[e] > logit[i1]) i1 = e;
    }

    // un-normalized top-k softmax scores (denominator over ALL experts)
    const float mx = logit[i0];
    float den = 0.f;
#pragma unroll
    for (int e = 0; e < NE; ++e) den += __expf(logit[e] - mx);
    const float w0 = __expf(logit[i0] - mx) / den;
    const float w1 = __expf(logit[i1] - mx) / den;

    const int   sel[2] = { i0, i1 };
    const float wk[2]  = { w0, w1 };
    float cf[8];
#pragma unroll
    for (int k = 0; k < 2; ++k) {
        // left[e][d][0..3] is one float4 at (e*1024 + d)
        const float4* l4 = reinterpret_cast<const float4*>(left + (size_t)sel[k] * (DIM * NR));
        float tx = 0.f, ty = 0.f, tz = 0.f, tw = 0.f;
#pragma unroll
        for (int i = 0; i < 4; ++i) {
            const int dq = (lane + i * 64) * 4;
            const float xv[4] = { xr[i].x, xr[i].y, xr[i].z, xr[i].w };
#pragma unroll
            for (int c = 0; c < 4; ++c) {
                float4 lv = l4[dq + c];
                tx += xv[c] * lv.x;
                ty += xv[c] * lv.y;
                tz += xv[c] * lv.z;
                tw += xv[c] * lv.w;
            }
        }
#pragma unroll
        for (int off = 32; off > 0; off >>= 1) {
            tx += __shfl_xor(tx, off, 64);
            ty += __shfl_xor(ty, off, 64);
            tz += __shfl_xor(tz, off, 64);
            tw += __shfl_xor(tw, off, 64);
        }
        cf[k * 4 + 0] = wk[k] * tx;
        cf[k * 4 + 1] = wk[k] * ty;
        cf[k * 4 + 2] = wk[k] * tz;
        cf[k * 4 + 3] = wk[k] * tw;
    }

    if (lane == 0) {
#pragma unroll
        for (int j = 0; j < 8; ++j) coef[(size_t)n * 8 + j] = cf[j];
        idxs[n * 2 + 0] = i0;
        idxs[n * 2 + 1] = i1;
    }
}

// ---------------------------------------------------------------------------
// Kernel 2: base = x @ W^T + b, bf16 MFMA 16x16x32, 128x128 tile, BK=64,
// 4 waves (2x2), each wave owns a 64x64 sub-tile (4x4 fragments).
// fp32 global loads -> bf16 convert -> LDS (padded stride 72).
// ---------------------------------------------------------------------------
#define BM 128
#define BN 128
#define BK 64
#define LDSS 72

__global__ __launch_bounds__(256) void base_gemm_kernel(
    const float* __restrict__ x, const float* __restrict__ W,
    const float* __restrict__ bias, float* __restrict__ out)
{
    __shared__ __align__(16) bf16_t As[BM * LDSS];
    __shared__ __align__(16) bf16_t Bs[BN * LDSS];

    const int tid  = threadIdx.x;
    const int lane = tid & 63;
    const int wid  = tid >> 6;
    const int wm   = wid >> 1;       // 0..1
    const int wn   = wid & 1;        // 0..1
    const int bm   = blockIdx.x >> 3;  // 128 row tiles
    const int bn   = blockIdx.x & 7;   // 8 col tiles

    f32x4_t acc[4][4] = {};

    const int srow = tid >> 4;          // 0..15
    const int scol = (tid & 15) * 4;    // 0..60
    const float* xp = x + (size_t)(bm * BM + srow) * DIM + scol;
    const float* wp = W + (size_t)(bn * BN + srow) * DIM + scol;

    const int lrow = lane & 15;
    const int lko  = (lane >> 4) * 8;

    for (int kt = 0; kt < DIM; kt += BK) {
        // stage A (x rows) and B (W rows = output cols) with fp32->bf16 convert
#pragma unroll
        for (int p = 0; p < 8; ++p) {
            float4 av = *reinterpret_cast<const float4*>(xp + (size_t)p * 16 * DIM + kt);
            float4 wv = *reinterpret_cast<const float4*>(wp + (size_t)p * 16 * DIM + kt);
            bf16x4_t ab, bb;
            ab[0] = (bf16_t)av.x; ab[1] = (bf16_t)av.y; ab[2] = (bf16_t)av.z; ab[3] = (bf16_t)av.w;
            bb[0] = (bf16_t)wv.x; bb[1] = (bf16_t)wv.y; bb[2] = (bf16_t)wv.z; bb[3] = (bf16_t)wv.w;
            *reinterpret_cast<bf16x4_t*>(&As[(srow + p * 16) * LDSS + scol]) = ab;
            *reinterpret_cast<bf16x4_t*>(&Bs[(srow + p * 16) * LDSS + scol]) = bb;
        }
        __syncthreads();

#pragma unroll
        for (int kk = 0; kk < 2; ++kk) {
            bf16x8_t afrag[4], bfrag[4];
            const int ko = kk * 32 + lko;
#pragma unroll
            for (int f = 0; f < 4; ++f) {
                afrag[f] = *reinterpret_cast<const bf16x8_t*>(&As[(wm * 64 + f * 16 + lrow) * LDSS + ko]);
                bfrag[f] = *reinterpret_cast<const bf16x8_t*>(&Bs[(wn * 64 + f * 16 + lrow) * LDSS + ko]);
            }
#pragma unroll
            for (int i = 0; i < 4; ++i)
#pragma unroll
                for (int j = 0; j < 4; ++j)
                    acc[i][j] = __builtin_amdgcn_mfma_f32_16x16x32_bf16(
                        afrag[i], bfrag[j], acc[i][j], 0, 0, 0);
        }
        __syncthreads();
    }

    // epilogue: C/D layout col=lane&15, row=(lane>>4)*4+v
    const int row0 = bm * BM + wm * 64 + (lane >> 4) * 4;
    const int col0 = bn * BN + wn * 64 + lrow;
#pragma unroll
    for (int j = 0; j < 4; ++j) {
        const int col = col0 + j * 16;
        const float bv = bias[col];
#pragma unroll
        for (int i = 0; i < 4; ++i) {
#pragma unroll
            for (int v = 0; v < 4; ++v) {
                out[(size_t)(row0 + i * 16 + v) * DIM + col] = acc[i][j][v] + bv;
            }
        }
    }
}

// ---------------------------------------------------------------------------
// Kernel 3: out[n][o] += sum_{k,r} coef[n][k*4+r] * right[idx[n][k]][r][o]
// one block per token; right (128 KB) stays L2-hot.
// ---------------------------------------------------------------------------
__global__ __launch_bounds__(256) void lora_add_kernel(
    const float* __restrict__ right, const float* __restrict__ coef,
    const int* __restrict__ idxs, float* __restrict__ out)
{
    const int n  = blockIdx.x;
    const int e0 = idxs[n * 2 + 0];
    const int e1 = idxs[n * 2 + 1];
    float c[8];
#pragma unroll
    for (int j = 0; j < 8; ++j) c[j] = coef[(size_t)n * 8 + j];
    const float* r0 = right + (size_t)e0 * (NR * DIM);
    const float* r1 = right + (size_t)e1 * (NR * DIM);
    float* op = out + (size_t)n * DIM;
#pragma unroll
    for (int j = 0; j < 4; ++j) {
        const int o = threadIdx.x + j * 256;
        float a = op[o];
#pragma unroll
        for (int r = 0; r < 4; ++r)
            a += c[r] * r0[r * DIM + o] + c[4 + r] * r1[r * DIM + o];
        op[o] = a;
    }
}

// ---------------------------------------------------------------------------
extern "C" void kernel_launch(void* const* d_in, const int* in_sizes, int n_in,
                              void* d_out, int out_size, void* d_ws, size_t ws_size,
                              hipStream_t stream)
{
    const float* x     = (const float*)d_in[0];   // [16384,1024]
    const float* W     = (const float*)d_in[1];   // [1024,1024]
    const float* bias  = (const float*)d_in[2];   // [1024]
    const float* gw    = (const float*)d_in[3];   // [8,1024]
    const float* left  = (const float*)d_in[4];   // [8,1024,4]
    const float* right = (const float*)d_in[5];   // [8,4,1024]
    float* out = (float*)d_out;                   // [16384,1024]

    float* coef = (float*)d_ws;                                       // 16384*8 f32
    int*   idxs = (int*)((char*)d_ws + (size_t)N_TOK * 8 * sizeof(float)); // 16384*2 i32

    gate_coef_kernel<<<N_TOK / 4, 256, 0, stream>>>(x, gw, left, coef, idxs);
    base_gemm_kernel<<<(N_TOK / BM) * (DIM / BN), 256, 0, stream>>>(x, W, bias, out);
    lora_add_kernel<<<N_TOK, 256, 0, stream>>>(right, coef, idxs, out);
}